// Round 3
// baseline (138.884 us; speedup 1.0000x reference)
//
#include <hip/hip_runtime.h>
#include <cstdint>
#include <cstddef>

#define B_ 4
#define N_ 4096
#define DIN_ 128

typedef __attribute__((ext_vector_type(8))) short short8;
typedef __attribute__((ext_vector_type(4))) float f32x4;
typedef __attribute__((ext_vector_type(4))) unsigned short us4;

__device__ __forceinline__ unsigned short f2bf(float f) {
    union { float f; unsigned int i; } v; v.f = f;
    unsigned int i = v.i;
    return (unsigned short)((i + 0x7FFFu + ((i >> 16) & 1u)) >> 16);
}

__device__ __forceinline__ float fast_sqrtf(float x) {
#if defined(__has_builtin)
#if __has_builtin(__builtin_amdgcn_sqrtf)
    return __builtin_amdgcn_sqrtf(x);
#else
    return sqrtf(x);
#endif
#else
    return sqrtf(x);
#endif
}

// ---------------- projection: x[R,128] @ {Wq,Wk,Wv}[128,64] ----------------
// grid (256 row-tiles, 3 projs), 256 threads. Whole W (32KB) + x tile (33KB)
// staged in LDS; thread computes 4 rows x 4 cols, FMA-bound.
// Outputs: qb,kb bf16 [B*N][64]; vT bf16 [B][64][N]; qsq,ksq f32 [B*N].
__global__ __launch_bounds__(256, 2) void proj_kernel(
    const float* __restrict__ x, const float* __restrict__ Wq,
    const float* __restrict__ Wk, const float* __restrict__ Wv,
    unsigned short* __restrict__ qb, unsigned short* __restrict__ kb,
    unsigned short* __restrict__ vT, float* __restrict__ qsq,
    float* __restrict__ ksq)
{
    __shared__ float xl[64 * 132];     // 33792 B, padded rows
    __shared__ float wl[128 * 64];     // 32768 B
    const int t = threadIdx.x;
    const int R0 = blockIdx.x * 64;
    const int proj = blockIdx.y;
    const float* __restrict__ W = (proj == 0) ? Wq : ((proj == 1) ? Wk : Wv);

    // stage x tile [64][128] -> xl[64][132], coalesced float4
#pragma unroll
    for (int j = 0; j < 8; ++j) {
        const int i = t + 256 * j;          // 0..2047
        const int row = i >> 5, dc = i & 31;
        *(float4*)(&xl[row * 132 + dc * 4]) =
            *(const float4*)(x + (size_t)(R0 + row) * DIN_ + dc * 4);
    }
    // stage W [128][64] linear
#pragma unroll
    for (int j = 0; j < 8; ++j) {
        const int i = t + 256 * j;          // 0..2047
        *(float4*)(&wl[i * 4]) = *(const float4*)(W + (size_t)i * 4);
    }
    __syncthreads();

    const int cg = t & 15, rg = t >> 4;
    const int c0 = cg * 4, r0 = rg * 4;

    float acc[4][4];
#pragma unroll
    for (int r = 0; r < 4; ++r)
#pragma unroll
        for (int c = 0; c < 4; ++c) acc[r][c] = 0.f;

    for (int d4 = 0; d4 < 32; ++d4) {
        float4 xv[4];
#pragma unroll
        for (int r = 0; r < 4; ++r)
            xv[r] = *(const float4*)(&xl[(r0 + r) * 132 + d4 * 4]);
#pragma unroll
        for (int dd = 0; dd < 4; ++dd) {
            const float4 wv = *(const float4*)(&wl[(d4 * 4 + dd) * 64 + c0]);
            const float wc[4] = { wv.x, wv.y, wv.z, wv.w };
#pragma unroll
            for (int r = 0; r < 4; ++r) {
                const float xr = ((const float*)&xv[r])[dd];
#pragma unroll
                for (int c = 0; c < 4; ++c)
                    acc[r][c] = fmaf(xr, wc[c], acc[r][c]);
            }
        }
    }

    if (proj < 2) {
        unsigned short* dst0 = (proj == 0) ? qb : kb;
#pragma unroll
        for (int r = 0; r < 4; ++r) {
            us4 pk = { f2bf(acc[r][0]), f2bf(acc[r][1]),
                       f2bf(acc[r][2]), f2bf(acc[r][3]) };
            *(us4*)(dst0 + (size_t)(R0 + r0 + r) * 64 + c0) = pk;
        }
        // row squared-norms: reduce over the 16 col-groups (lane low-4 bits)
#pragma unroll
        for (int r = 0; r < 4; ++r) {
            float s = 0.f;
#pragma unroll
            for (int c = 0; c < 4; ++c) s = fmaf(acc[r][c], acc[r][c], s);
            s += __shfl_xor(s, 1);
            s += __shfl_xor(s, 2);
            s += __shfl_xor(s, 4);
            s += __shfl_xor(s, 8);
            if (cg == 0) {
                float* sq = (proj == 0) ? qsq : ksq;
                sq[R0 + r0 + r] = s;
            }
        }
    } else {
        // v: store transposed vT[b][e][n]; 4 consecutive n per store
        const int bb = R0 >> 12;
        const int n0 = (R0 & (N_ - 1)) + r0;
#pragma unroll
        for (int c = 0; c < 4; ++c) {
            us4 pk = { f2bf(acc[0][c]), f2bf(acc[1][c]),
                       f2bf(acc[2][c]), f2bf(acc[3][c]) };
            *(us4*)(vT + ((size_t)bb * 64 + (c0 + c)) * N_ + n0) = pk;
        }
    }
}

// ---------------- split-K flash attention (no-max online softmax) ----------
// grid (64 q-tiles, 4 batch, S splits); 256 threads = 4 waves; wave owns 16
// q-rows. Next K/V tile prefetched into registers during compute (T14).
__global__ __launch_bounds__(256, 5) void attn_kernel(
    const unsigned short* __restrict__ qb, const unsigned short* __restrict__ kb,
    const unsigned short* __restrict__ vT, const float* __restrict__ qsq,
    const float* __restrict__ ksq, float* __restrict__ Opart,
    float* __restrict__ Lpart, int ktn)
{
    __shared__ __align__(16) char smem[8192 * 2 + 8192 + 256];
    char* Klds = smem;                  // [64 k][64 d] bf16, XOR-swizzled rows
    char* Vlds = smem + 8192;           // [64 e][64 k] bf16, XOR-swizzled rows
    char* Plds = smem + 16384;          // 4 waves x [16][64] bf16, swizzled
    float* ksql = (float*)(smem + 24576);

    const int t = threadIdx.x;
    const int w = t >> 6;
    const int lane = t & 63;
    const int li = lane & 15;
    const int g = lane >> 4;
    const int b = blockIdx.y;
    const int sp = blockIdx.z;
    const int q0 = blockIdx.x * 64;
    const int kt0 = sp * ktn;

    char* Pw = Plds + w * 2048;

    // Q A-fragments (row = li, d-slices g*8 and 32+g*8)
    const size_t qoff = ((size_t)b * N_ + q0 + w * 16 + li) * 64;
    const short8 qa0 = *(const short8*)(qb + qoff + g * 8);
    const short8 qa1 = *(const short8*)(qb + qoff + 32 + g * 8);

    float qsqr[4];
#pragma unroll
    for (int r = 0; r < 4; ++r)
        qsqr[r] = qsq[(size_t)b * N_ + q0 + w * 16 + g * 4 + r];

    f32x4 oa[4];
    float lsum[4];
#pragma unroll
    for (int i = 0; i < 4; ++i) {
        oa[i] = (f32x4){0.f, 0.f, 0.f, 0.f};
        lsum[i] = 0.f;
    }

    const unsigned short* kbb = kb + (size_t)b * N_ * 64;
    const unsigned short* vtb = vT + (size_t)b * 64 * N_;
    const float* ksqb = ksq + (size_t)b * N_;

    // staging geometry: thread handles chunks idx = t, t+256 (row = idx>>3, cc = idx&7)
    const int srow0 = t >> 3, scc0 = t & 7;
    const int srow1 = (t + 256) >> 3, scc1 = t & 7;
    const int slb0 = (srow0 * 128 + scc0 * 16) ^ ((srow0 & 7) << 4);
    const int slb1 = (srow1 * 128 + scc1 * 16) ^ ((srow1 & 7) << 4);

    // ---- prologue: stage tile kt0 directly ----
    {
        *(uint4*)(Klds + slb0) = *(const uint4*)(kbb + (size_t)(kt0 * 64 + srow0) * 64 + scc0 * 8);
        *(uint4*)(Klds + slb1) = *(const uint4*)(kbb + (size_t)(kt0 * 64 + srow1) * 64 + scc1 * 8);
        *(uint4*)(Vlds + slb0) = *(const uint4*)(vtb + (size_t)srow0 * N_ + kt0 * 64 + scc0 * 8);
        *(uint4*)(Vlds + slb1) = *(const uint4*)(vtb + (size_t)srow1 * N_ + kt0 * 64 + scc1 * 8);
        if (t < 64) ksql[t] = ksqb[kt0 * 64 + t];
    }
    __syncthreads();

    for (int ktl = 0; ktl < ktn; ++ktl) {
        const int kt = kt0 + ktl;
        // ---- T14: issue next tile's global loads into registers ----
        uint4 kn0, kn1, vn0, vn1;
        float ksn = 0.f;
        const bool more = (ktl + 1 < ktn);
        if (more) {
            const int ktn1 = kt + 1;
            kn0 = *(const uint4*)(kbb + (size_t)(ktn1 * 64 + srow0) * 64 + scc0 * 8);
            kn1 = *(const uint4*)(kbb + (size_t)(ktn1 * 64 + srow1) * 64 + scc1 * 8);
            vn0 = *(const uint4*)(vtb + (size_t)srow0 * N_ + ktn1 * 64 + scc0 * 8);
            vn1 = *(const uint4*)(vtb + (size_t)srow1 * N_ + ktn1 * 64 + scc1 * 8);
            if (t < 64) ksn = ksqb[ktn1 * 64 + t];
        }

        // ---- S = Q K^T, p = exp2(sqrt(relu(q2+k2-2s)) * 0.125*log2e) ----
#pragma unroll
        for (int c = 0; c < 4; ++c) {
            const int kr = c * 16 + li;
            const int sw = (kr & 7) << 4;
            const short8 kf0 = *(const short8*)(Klds + ((kr * 128 + g * 16) ^ sw));
            const short8 kf1 = *(const short8*)(Klds + ((kr * 128 + 64 + g * 16) ^ sw));
            const float ksv = ksql[kr];
            f32x4 s = (f32x4){0.f, 0.f, 0.f, 0.f};
            s = __builtin_amdgcn_mfma_f32_16x16x32_bf16(qa0, kf0, s, 0, 0, 0);
            s = __builtin_amdgcn_mfma_f32_16x16x32_bf16(qa1, kf1, s, 0, 0, 0);
#pragma unroll
            for (int r = 0; r < 4; ++r) {
                const float d2 = fmaf(-2.0f, s[r], qsqr[r] + ksv);
                const float dist = fast_sqrtf(fmaxf(d2, 0.0f));
                const float p = exp2f(dist * 0.1803368801f); // = exp(dist/8)
                lsum[r] += p;
                const int prow = g * 4 + r;
                *(unsigned short*)(Pw + ((prow * 128 + kr * 2) ^ ((prow & 7) << 4))) = f2bf(p);
            }
        }

        // ---- O += P @ V ----
        const int swp = (li & 7) << 4;
        const short8 pa0 = *(const short8*)(Pw + ((li * 128 + g * 16) ^ swp));
        const short8 pa1 = *(const short8*)(Pw + ((li * 128 + 64 + g * 16) ^ swp));
#pragma unroll
        for (int c2 = 0; c2 < 4; ++c2) {
            const int er = c2 * 16 + li;
            const int swv = (er & 7) << 4;
            const short8 vf0 = *(const short8*)(Vlds + ((er * 128 + g * 16) ^ swv));
            const short8 vf1 = *(const short8*)(Vlds + ((er * 128 + 64 + g * 16) ^ swv));
            oa[c2] = __builtin_amdgcn_mfma_f32_16x16x32_bf16(pa0, vf0, oa[c2], 0, 0, 0);
            oa[c2] = __builtin_amdgcn_mfma_f32_16x16x32_bf16(pa1, vf1, oa[c2], 0, 0, 0);
        }
        __syncthreads();   // all waves done reading K/V

        if (more) {
            *(uint4*)(Klds + slb0) = kn0;
            *(uint4*)(Klds + slb1) = kn1;
            *(uint4*)(Vlds + slb0) = vn0;
            *(uint4*)(Vlds + slb1) = vn1;
            if (t < 64) ksql[t] = ksn;
            __syncthreads();
        }
    }

    // ---- write partials (unnormalized) ----
    const size_t obase = ((size_t)sp * B_ + b) * N_;
#pragma unroll
    for (int r = 0; r < 4; ++r) {
        float srow = lsum[r];
        srow += __shfl_xor(srow, 1);
        srow += __shfl_xor(srow, 2);
        srow += __shfl_xor(srow, 4);
        srow += __shfl_xor(srow, 8);
        const int row = q0 + w * 16 + g * 4 + r;
        if (li == 0) Lpart[obase + row] = srow;
#pragma unroll
        for (int c2 = 0; c2 < 4; ++c2)
            Opart[(obase + row) * 64 + c2 * 16 + li] = oa[c2][r];
    }
}

// ---------------- combine splits + normalize ----------------
__global__ __launch_bounds__(256) void reduce_kernel(
    const float* __restrict__ Opart, const float* __restrict__ Lpart,
    float* __restrict__ out, int S)
{
    const int idx = blockIdx.x * 256 + threadIdx.x;   // 262144 threads
    const int rowg = idx >> 4;                        // 0..16383 (b*N+row)
    const int e4 = (idx & 15) << 2;
    float l = 0.f;
    float4 o = {0.f, 0.f, 0.f, 0.f};
    for (int s = 0; s < S; ++s) {
        l += Lpart[(size_t)s * (B_ * N_) + rowg];
        const float4 v = *(const float4*)(Opart + ((size_t)s * (B_ * N_) + rowg) * 64 + e4);
        o.x += v.x; o.y += v.y; o.z += v.z; o.w += v.w;
    }
    const float inv = 1.0f / l;
    const float4 res = {o.x * inv, o.y * inv, o.z * inv, o.w * inv};
    *(float4*)(out + (size_t)rowg * 64 + e4) = res;
}

extern "C" void kernel_launch(void* const* d_in, const int* in_sizes, int n_in,
                              void* d_out, int out_size, void* d_ws, size_t ws_size,
                              hipStream_t stream) {
    (void)in_sizes; (void)n_in; (void)out_size;
    const float* x  = (const float*)d_in[0];
    const float* Wq = (const float*)d_in[1];
    const float* Wk = (const float*)d_in[2];
    const float* Wv = (const float*)d_in[3];

    char* ws = (char*)d_ws;
    const size_t MB = 1024 * 1024;
    unsigned short* qb = (unsigned short*)(ws);                 // 2 MB
    unsigned short* kb = (unsigned short*)(ws + 2 * MB);        // 2 MB
    unsigned short* vT = (unsigned short*)(ws + 4 * MB);        // 2 MB
    float* qsq = (float*)(ws + 6 * MB);                         // 64 KB
    float* ksq = (float*)(ws + 6 * MB + 65536);                 // 64 KB
    float* Lpart = (float*)(ws + 6 * MB + 262144);              // <= 512 KB

    int S;
    float* Opart;
    if (ws_size >= 7 * MB + 32 * MB)      { S = 8; Opart = (float*)(ws + 7 * MB); }
    else if (ws_size >= 7 * MB + 16 * MB) { S = 4; Opart = (float*)(ws + 7 * MB); }
    else if (ws_size >= 7 * MB + 8 * MB)  { S = 2; Opart = (float*)(ws + 7 * MB); }
    else if (ws_size >= 7 * MB + 4 * MB)  { S = 1; Opart = (float*)(ws + 7 * MB); }
    else                                  { S = 1; Opart = (float*)d_out; }

    hipLaunchKernelGGL(proj_kernel, dim3(256, 3), dim3(256), 0, stream,
                       x, Wq, Wk, Wv, qb, kb, vT, qsq, ksq);
    hipLaunchKernelGGL(attn_kernel, dim3(64, B_, S), dim3(256), 0, stream,
                       qb, kb, vT, qsq, ksq, Opart, Lpart, 64 / S);
    hipLaunchKernelGGL(reduce_kernel, dim3(1024), dim3(256), 0, stream,
                       Opart, Lpart, (float*)d_out, S);
}

// Round 5
// 68.028 us; speedup vs baseline: 2.0416x; 2.0416x over previous
//
#include <hip/hip_runtime.h>
#include <cstdint>
#include <cstddef>

#define B_ 4
#define N_ 4096
#define DIN_ 128

// c = log2(e)/8 ; C2 = c^2 ; exp(dist/8) = exp2(sqrt(d2 * C2))
#define C2_ 0.0325213905f
#define NEG2C2_ (-0.0650427810f)

typedef __attribute__((ext_vector_type(8))) short short8;
typedef __attribute__((ext_vector_type(4))) float f32x4;
typedef __attribute__((ext_vector_type(4))) unsigned short us4;

__device__ __forceinline__ unsigned short f2bf(float f) {
    union { float f; unsigned int i; } v; v.f = f;
    unsigned int i = v.i;
    return (unsigned short)((i + 0x7FFFu + ((i >> 16) & 1u)) >> 16);
}

__device__ __forceinline__ unsigned int cvt_pk_bf16(float lo, float hi) {
    unsigned int r;
    asm("v_cvt_pk_bf16_f32 %0, %1, %2" : "=v"(r) : "v"(lo), "v"(hi));
    return r;
}

// ---------------- projection: x[R,128] @ {Wq,Wk,Wv}[128,64] ----------------
// grid (256 row-tiles, 3 projs), 256 threads. Whole W (32KB) + x tile (33KB)
// staged in LDS; thread computes 4 rows x 4 cols, FMA-bound.
__global__ __launch_bounds__(256, 2) void proj_kernel(
    const float* __restrict__ x, const float* __restrict__ Wq,
    const float* __restrict__ Wk, const float* __restrict__ Wv,
    unsigned short* __restrict__ qb, unsigned short* __restrict__ kb,
    unsigned short* __restrict__ vT, float* __restrict__ qsq,
    float* __restrict__ ksq)
{
    __shared__ float xl[64 * 132];
    __shared__ float wl[128 * 64];
    const int t = threadIdx.x;
    const int R0 = blockIdx.x * 64;
    const int proj = blockIdx.y;
    const float* __restrict__ W = (proj == 0) ? Wq : ((proj == 1) ? Wk : Wv);

#pragma unroll
    for (int j = 0; j < 8; ++j) {
        const int i = t + 256 * j;
        const int row = i >> 5, dc = i & 31;
        *(float4*)(&xl[row * 132 + dc * 4]) =
            *(const float4*)(x + (size_t)(R0 + row) * DIN_ + dc * 4);
    }
#pragma unroll
    for (int j = 0; j < 8; ++j) {
        const int i = t + 256 * j;
        *(float4*)(&wl[i * 4]) = *(const float4*)(W + (size_t)i * 4);
    }
    __syncthreads();

    const int cg = t & 15, rg = t >> 4;
    const int c0 = cg * 4, r0 = rg * 4;

    float acc[4][4];
#pragma unroll
    for (int r = 0; r < 4; ++r)
#pragma unroll
        for (int c = 0; c < 4; ++c) acc[r][c] = 0.f;

    for (int d4 = 0; d4 < 32; ++d4) {
        float4 xv[4];
#pragma unroll
        for (int r = 0; r < 4; ++r)
            xv[r] = *(const float4*)(&xl[(r0 + r) * 132 + d4 * 4]);
#pragma unroll
        for (int dd = 0; dd < 4; ++dd) {
            const float4 wv = *(const float4*)(&wl[(d4 * 4 + dd) * 64 + c0]);
            const float wc[4] = { wv.x, wv.y, wv.z, wv.w };
#pragma unroll
            for (int r = 0; r < 4; ++r) {
                const float xr = ((const float*)&xv[r])[dd];
#pragma unroll
                for (int c = 0; c < 4; ++c)
                    acc[r][c] = fmaf(xr, wc[c], acc[r][c]);
            }
        }
    }

    if (proj < 2) {
        unsigned short* dst0 = (proj == 0) ? qb : kb;
#pragma unroll
        for (int r = 0; r < 4; ++r) {
            us4 pk = { f2bf(acc[r][0]), f2bf(acc[r][1]),
                       f2bf(acc[r][2]), f2bf(acc[r][3]) };
            *(us4*)(dst0 + (size_t)(R0 + r0 + r) * 64 + c0) = pk;
        }
#pragma unroll
        for (int r = 0; r < 4; ++r) {
            float s = 0.f;
#pragma unroll
            for (int c = 0; c < 4; ++c) s = fmaf(acc[r][c], acc[r][c], s);
            s += __shfl_xor(s, 1);
            s += __shfl_xor(s, 2);
            s += __shfl_xor(s, 4);
            s += __shfl_xor(s, 8);
            if (cg == 0) {
                float* sq = (proj == 0) ? qsq : ksq;
                sq[R0 + r0 + r] = s;
            }
        }
    } else {
        const int bb = R0 >> 12;
        const int n0 = (R0 & (N_ - 1)) + r0;
#pragma unroll
        for (int c = 0; c < 4; ++c) {
            us4 pk = { f2bf(acc[0][c]), f2bf(acc[1][c]),
                       f2bf(acc[2][c]), f2bf(acc[3][c]) };
            *(us4*)(vT + ((size_t)bb * 64 + (c0 + c)) * N_ + n0) = pk;
        }
    }
}

// ---------------- split-K flash attention, swapped QK^T ----------
// grid (64 q-tiles, 4 batch, 8 splits); 256 threads = 4 waves x 16 q-rows.
// Swapped mfma(K,Q): lane (li,g) holds P[q=li][k=c*16+g*4+r] -> packed
// cvt_pk_bf16 + ds_write_b64, scalar lsum, float4 ksq. LDS 24.8KB -> 6 blk/CU.
__global__ __launch_bounds__(256, 6) void attn_kernel(
    const unsigned short* __restrict__ qb, const unsigned short* __restrict__ kb,
    const unsigned short* __restrict__ vT, const float* __restrict__ qsq,
    const float* __restrict__ ksq, float* __restrict__ Opart,
    float* __restrict__ Lpart, int ktn)
{
    __shared__ __align__(16) char smem[24576 + 256];
    char* Klds = smem;                  // [64 k][64 d] bf16, XOR-swizzled rows
    char* Vlds = smem + 8192;           // [64 e][64 k] bf16, XOR-swizzled rows
    char* Plds = smem + 16384;          // 4 waves x [16 q][64 k] bf16, swizzled
    float* ksql = (float*)(smem + 24576);   // 64 f32, pre-scaled by C2

    const int t = threadIdx.x;
    const int w = t >> 6, lane = t & 63, li = lane & 15, g = lane >> 4;
    const int b = blockIdx.y, sp = blockIdx.z;
    const int q0 = blockIdx.x * 64;
    const int kt0 = sp * ktn;
    char* Pw = Plds + w * 2048;

    // Q fragment: lane li holds row (q0+w*16+li), d-slices g*8 and 32+g*8.
    // Used as the MFMA *B* operand (B-frag col=li == A-frag row=li content).
    const size_t qoff = ((size_t)b * N_ + q0 + w * 16 + li) * 64;
    const short8 qa0 = *(const short8*)(qb + qoff + g * 8);
    const short8 qa1 = *(const short8*)(qb + qoff + 32 + g * 8);
    const float qsc = qsq[(size_t)b * N_ + q0 + w * 16 + li] * C2_;

    f32x4 oa[4];
#pragma unroll
    for (int i = 0; i < 4; ++i) oa[i] = (f32x4){0.f, 0.f, 0.f, 0.f};
    float lsum = 0.f;

    const unsigned short* kbb = kb + (size_t)b * N_ * 64;
    const unsigned short* vtb = vT + (size_t)b * 64 * N_;
    const float* ksqb = ksq + (size_t)b * N_;

    // staging: 512 16B-chunks, 2 per thread (rows t>>3 and +32)
    const int row0 = t >> 3, cc0 = t & 7;
    const int row1 = row0 + 32;
    const int lb0 = (row0 * 128 + cc0 * 16) ^ ((row0 & 7) << 4);
    const int lb1 = (row1 * 128 + cc0 * 16) ^ ((row1 & 7) << 4);

    for (int ktl = 0; ktl < ktn; ++ktl) {
        const int kt = kt0 + ktl;
        *(uint4*)(Klds + lb0) = *(const uint4*)(kbb + (size_t)(kt * 64 + row0) * 64 + cc0 * 8);
        *(uint4*)(Klds + lb1) = *(const uint4*)(kbb + (size_t)(kt * 64 + row1) * 64 + cc0 * 8);
        *(uint4*)(Vlds + lb0) = *(const uint4*)(vtb + (size_t)row0 * N_ + kt * 64 + cc0 * 8);
        *(uint4*)(Vlds + lb1) = *(const uint4*)(vtb + (size_t)row1 * N_ + kt * 64 + cc0 * 8);
        if (t < 64) ksql[t] = ksqb[kt * 64 + t] * C2_;
        __syncthreads();

        // ---- S^T = K Q^T (swapped): sacc[c][r] = S[k=c*16+g*4+r][q=li] ----
#pragma unroll
        for (int c = 0; c < 4; ++c) {
            const int kr = c * 16 + li;
            const int sw = (kr & 7) << 4;
            const short8 kf0 = *(const short8*)(Klds + ((kr * 128 + g * 16) ^ sw));
            const short8 kf1 = *(const short8*)(Klds + ((kr * 128 + 64 + g * 16) ^ sw));
            f32x4 s = (f32x4){0.f, 0.f, 0.f, 0.f};
            s = __builtin_amdgcn_mfma_f32_16x16x32_bf16(kf0, qa0, s, 0, 0, 0);
            s = __builtin_amdgcn_mfma_f32_16x16x32_bf16(kf1, qa1, s, 0, 0, 0);

            const float4 ksc = *(const float4*)(ksql + c * 16 + g * 4);
            const float kscv[4] = { ksc.x, ksc.y, ksc.z, ksc.w };
            float p[4];
#pragma unroll
            for (int r = 0; r < 4; ++r) {
                const float d2 = fmaf(NEG2C2_, s[r], qsc + kscv[r]);
                const float ds = __builtin_amdgcn_sqrtf(fmaxf(d2, 0.0f));
                p[r] = exp2f(ds);
                lsum += p[r];
            }
            // packed P write: row li, k-bytes c*32+g*8 .. +7
            uint2 pk;
            pk.x = cvt_pk_bf16(p[0], p[1]);
            pk.y = cvt_pk_bf16(p[2], p[3]);
            *(uint2*)(Pw + ((li * 128 + c * 32 + g * 8) ^ ((li & 7) << 4))) = pk;
        }

        // ---- O += P @ V : A = P[q=li][k g*8+j], B = V frags ----
        const int swp = (li & 7) << 4;
        const short8 pa0 = *(const short8*)(Pw + ((li * 128 + g * 16) ^ swp));
        const short8 pa1 = *(const short8*)(Pw + ((li * 128 + 64 + g * 16) ^ swp));
#pragma unroll
        for (int c2 = 0; c2 < 4; ++c2) {
            const int er = c2 * 16 + li;
            const int swv = (er & 7) << 4;
            const short8 vf0 = *(const short8*)(Vlds + ((er * 128 + g * 16) ^ swv));
            const short8 vf1 = *(const short8*)(Vlds + ((er * 128 + 64 + g * 16) ^ swv));
            oa[c2] = __builtin_amdgcn_mfma_f32_16x16x32_bf16(pa0, vf0, oa[c2], 0, 0, 0);
            oa[c2] = __builtin_amdgcn_mfma_f32_16x16x32_bf16(pa1, vf1, oa[c2], 0, 0, 0);
        }
        __syncthreads();
    }

    // ---- write partials (unnormalized) ----
    const size_t obase = ((size_t)sp * B_ + b) * N_;
    lsum += __shfl_xor(lsum, 16);
    lsum += __shfl_xor(lsum, 32);
    if (lane < 16) Lpart[obase + q0 + w * 16 + li] = lsum;
#pragma unroll
    for (int c2 = 0; c2 < 4; ++c2)
#pragma unroll
        for (int r = 0; r < 4; ++r)
            Opart[(obase + q0 + w * 16 + g * 4 + r) * 64 + c2 * 16 + li] = oa[c2][r];
}

// ---------------- combine splits + normalize ----------------
__global__ __launch_bounds__(256) void reduce_kernel(
    const float* __restrict__ Opart, const float* __restrict__ Lpart,
    float* __restrict__ out, int S)
{
    const int idx = blockIdx.x * 256 + threadIdx.x;
    const int rowg = idx >> 4;
    const int e4 = (idx & 15) << 2;
    float l = 0.f;
    float4 o = {0.f, 0.f, 0.f, 0.f};
    for (int s = 0; s < S; ++s) {
        l += Lpart[(size_t)s * (B_ * N_) + rowg];
        const float4 v = *(const float4*)(Opart + ((size_t)s * (B_ * N_) + rowg) * 64 + e4);
        o.x += v.x; o.y += v.y; o.z += v.z; o.w += v.w;
    }
    const float inv = 1.0f / l;
    const float4 res = {o.x * inv, o.y * inv, o.z * inv, o.w * inv};
    *(float4*)(out + (size_t)rowg * 64 + e4) = res;
}

extern "C" void kernel_launch(void* const* d_in, const int* in_sizes, int n_in,
                              void* d_out, int out_size, void* d_ws, size_t ws_size,
                              hipStream_t stream) {
    (void)in_sizes; (void)n_in; (void)out_size;
    const float* x  = (const float*)d_in[0];
    const float* Wq = (const float*)d_in[1];
    const float* Wk = (const float*)d_in[2];
    const float* Wv = (const float*)d_in[3];

    char* ws = (char*)d_ws;
    const size_t MB = 1024 * 1024;
    unsigned short* qb = (unsigned short*)(ws);                 // 2 MB
    unsigned short* kb = (unsigned short*)(ws + 2 * MB);        // 2 MB
    unsigned short* vT = (unsigned short*)(ws + 4 * MB);        // 2 MB
    float* qsq = (float*)(ws + 6 * MB);                         // 64 KB
    float* ksq = (float*)(ws + 6 * MB + 65536);                 // 64 KB
    float* Lpart = (float*)(ws + 6 * MB + 262144);              // <= 512 KB

    int S;
    float* Opart;
    if (ws_size >= 7 * MB + 32 * MB)      { S = 8; Opart = (float*)(ws + 7 * MB); }
    else if (ws_size >= 7 * MB + 16 * MB) { S = 4; Opart = (float*)(ws + 7 * MB); }
    else if (ws_size >= 7 * MB + 8 * MB)  { S = 2; Opart = (float*)(ws + 7 * MB); }
    else if (ws_size >= 7 * MB + 4 * MB)  { S = 1; Opart = (float*)(ws + 7 * MB); }
    else                                  { S = 1; Opart = (float*)d_out; }

    hipLaunchKernelGGL(proj_kernel, dim3(256, 3), dim3(256), 0, stream,
                       x, Wq, Wk, Wv, qb, kb, vT, qsq, ksq);
    hipLaunchKernelGGL(attn_kernel, dim3(64, B_, S), dim3(256), 0, stream,
                       qb, kb, vT, qsq, ksq, Opart, Lpart, 64 / S);
    hipLaunchKernelGGL(reduce_kernel, dim3(1024), dim3(256), 0, stream,
                       Opart, Lpart, (float*)d_out, S);
}